// Round 3
// baseline (1111.798 us; speedup 1.0000x reference)
//
#include <hip/hip_runtime.h>
#include <hip/hip_fp16.h>

// Problem constants: B=64, T=256, Wc=16, V=100000, Cv=100, K=9
#define NB_B 64
#define NT 256
#define NWC 16

__device__ __forceinline__ float sigf(float x){ return 1.0f/(1.0f + __expf(-x)); }
__device__ __forceinline__ float tanhf_(float x){ return 1.0f - 2.0f/(__expf(2.0f*x)+1.0f); }

typedef _Float16 h2_t __attribute__((ext_vector_type(2)));

__device__ __forceinline__ float dot2f(unsigned int w, unsigned int x, float acc){
#if __has_builtin(__builtin_amdgcn_fdot2)
  return __builtin_amdgcn_fdot2(__builtin_bit_cast(h2_t, w), __builtin_bit_cast(h2_t, x), acc, false);
#else
  h2_t a = __builtin_bit_cast(h2_t, w), b = __builtin_bit_cast(h2_t, x);
  return acc + (float)a[0]*(float)b[0] + (float)a[1]*(float)b[1];
#endif
}

__device__ __forceinline__ unsigned int packh2(float a, float b){
  return ((unsigned int)__half_as_ushort(__float2half(a))) |
         (((unsigned int)__half_as_ushort(__float2half(b))) << 16);
}

// ---------------- prep kernels ----------------

__global__ void k_transpose(const float* __restrict__ src, float* __restrict__ dst, int R, int C){
  int idx = blockIdx.x*256 + threadIdx.x;
  if (idx < R*C){ int r = idx / C, c = idx % C; dst[c*R + r] = src[idx]; }
}

// ctx weights: wihP k-major [dir][k(0..99)][j] (coalesced for k_gx);
// whhQ k4-major uint4 [dir][k4(0..15)][j][4] (coalesced dwordx4 for k_ctx_rec);
// biasc[dir][j] fp32 (consumed by k_gx).
__global__ void k_prep_ctx(const float* __restrict__ wih_f, const float* __restrict__ whh_f,
                           const float* __restrict__ bih_f, const float* __restrict__ bhh_f,
                           const float* __restrict__ wih_b, const float* __restrict__ whh_b,
                           const float* __restrict__ bih_b, const float* __restrict__ bhh_b,
                           unsigned int* __restrict__ wihP, unsigned int* __restrict__ whhQ,
                           float* __restrict__ biasc){
  int idx = blockIdx.x*256 + threadIdx.x;
  const int NIH = 2*100*512, NHH = 2*16*512*4;
  if (idx < NIH){
    int dir = idx / (100*512); int r = idx % (100*512); int k = r >> 9; int j = r & 511;
    const float* wih = dir ? wih_b : wih_f;
    wihP[idx] = packh2(wih[j*200 + 2*k], wih[j*200 + 2*k + 1]);
  } else if (idx < NIH + NHH){
    int i2 = idx - NIH;
    int dir = i2 / 32768; int r = i2 % 32768;
    int k4 = r / 2048; int r2 = r % 2048; int j = r2 >> 2; int e = r2 & 3;
    const float* whh = dir ? whh_b : whh_f;
    whhQ[i2] = packh2(whh[j*128 + 8*k4 + 2*e], whh[j*128 + 8*k4 + 2*e + 1]);
  } else if (idx < NIH + NHH + 1024){
    int i2 = idx - NIH - NHH; int dir = i2 >> 9; int j = i2 & 511;
    biasc[i2] = dir ? (bih_b[j] + bhh_b[j]) : (bih_f[j] + bhh_f[j]);
  }
}

// char-LSTM x-projection table, gate-packed fp32
__global__ void k_prep_P4(const float* __restrict__ emb,
                          const float* __restrict__ wih_f, const float* __restrict__ bih_f, const float* __restrict__ bhh_f,
                          const float* __restrict__ wih_b, const float* __restrict__ bih_b, const float* __restrict__ bhh_b,
                          float4* __restrict__ P4){
  int idx = blockIdx.x*256 + threadIdx.x;
  if (idx >= 10000) return;               // 2 * 100 * 50
  int dir = idx / 5000; int r = idx % 5000; int c = r / 50; int u = r % 50;
  const float* wih = dir ? wih_b : wih_f;
  const float* bih = dir ? bih_b : bih_f;
  const float* bhh = dir ? bhh_b : bhh_f;
  float g4[4];
  #pragma unroll
  for (int gt = 0; gt < 4; gt++){
    int j = gt*50 + u;
    float acc = bih[j] + bhh[j];
    for (int k = 0; k < 30; k++) acc += emb[c*30 + k] * wih[j*30 + k];
    g4[gt] = acc;
  }
  P4[idx] = make_float4(g4[0], g4[1], g4[2], g4[3]);
}

// char-LSTM recurrent weights (R8/v2 layout): W2[dir][u][gate][k(0..24)]
__global__ void k_prep_whh2(const float* __restrict__ whh_f, const float* __restrict__ whh_b,
                            unsigned int* __restrict__ W2){
  int idx = blockIdx.x*256 + threadIdx.x;
  if (idx >= 10000) return;               // 2 * 50 * 4 * 25
  int dir = idx / 5000; int r = idx % 5000;
  int u = r / 100; int r2 = r % 100; int gt = r2 / 25; int k = r2 % 25;
  const float* whh = dir ? whh_b : whh_f;
  int j = gt*50 + u;
  W2[idx] = packh2(whh[j*50 + 2*k], whh[j*50 + 2*k + 1]);
}

// char-CNN lookup tables
__global__ void k_prep_Q(const float* __restrict__ emb, const float* __restrict__ w3,
                         const float* __restrict__ w5, const float* __restrict__ w7,
                         float* __restrict__ Q){
  int idx = blockIdx.x*256 + threadIdx.x;
  if (idx >= 48000) return;
  const float* w; int ks, r;
  if (idx < 9600){ w = w3; ks = 3; r = idx; }
  else if (idx < 25600){ w = w5; ks = 5; r = idx - 9600; }
  else { w = w7; ks = 7; r = idx - 25600; }
  int t = r / 3200; int o = (r / 100) % 32; int c = r % 100;
  float acc = 0.f;
  for (int i = 0; i < 30; i++) acc += emb[c*30 + i] * w[(o*30 + i)*ks + t];
  Q[idx] = acc;
}

// ---------------- feature construction ----------------

__global__ void k_gather(const int* __restrict__ word_ids, const float* __restrict__ word_emb,
                         float* __restrict__ combined){
  int idx = blockIdx.x*256 + threadIdx.x;
  if (idx >= NB_B*NT*200) return;
  int bt = idx / 200; int k = idx - bt*200;
  combined[bt*396 + k] = word_emb[(long)word_ids[bt]*200 + k];
}

// char CNN v2 (kept from R9): lane = output channel, Q staged in LDS [t][c][o]
template<int KS>
__global__ __launch_bounds__(512) void k_cnn2(const int* __restrict__ char_ids,
                                              const float* __restrict__ Qg,
                                              const float* __restrict__ bias,
                                              float* __restrict__ combined,
                                              int outoff){
  constexpr int PAD = KS/2;
  const int tid = threadIdx.x;
  __shared__ float Qlds[KS*3200];
  for (int idx = tid; idx < KS*3200; idx += 512){
    int t = idx / 3200; int r = idx - t*3200; int cc = r >> 5; int oo = r & 31;
    Qlds[idx] = Qg[(t*32 + oo)*100 + cc];
  }
  __syncthreads();
  const int o    = tid & 31;
  const int word = blockIdx.x*16 + ((tid >> 6) << 1) + ((tid >> 5) & 1);
  int ch[16];
  #pragma unroll
  for (int p = 0; p < 16; p++) ch[p] = char_ids[word*16 + p];
  float m = -1e30f;
  #pragma unroll
  for (int p = 0; p < 16; p++){
    float acc = 0.f;
    #pragma unroll
    for (int t = 0; t < KS; t++){
      int pp = p + t - PAD;
      if (pp >= 0 && pp < 16) acc += Qlds[(t*100 + ch[pp])*32 + o];
    }
    m = fmaxf(m, acc);
  }
  combined[(long)word*396 + 200 + outoff + o] = fmaxf(m + bias[o], 0.f);
}

// char LSTM v4 (R11, resubmitted R12 after container failure): scratch
// elimination. R10's VGPR_Count=36 + 273 MB WRITE_SIZE was localMem spill
// traffic, NOT store amplification:
//   - ch[16] runtime-indexed by t (unroll 1)          -> scratch (rule #20)
//   - pg[]/c[]/hval[] under PARTIAL (#pragma unroll 2) -> u runtime -> scratch
// Fix: cid re-loaded from L2-resident char_ids each step (prefetched 1 ahead),
// u-loop FULLY unrolled (static indices -> registers), min-waves 5->4 so the
// ~90 live regs fit under the 128-VGPR cap without spilling.
__global__ __launch_bounds__(640, 4) void k_char_lstm(const int* __restrict__ char_ids,
                                                      const float4* __restrict__ P4,
                                                      const unsigned int* __restrict__ W2,
                                                      float* __restrict__ combined){
  const int lane = threadIdx.x & 63;                                  // word in block
  const int g5   = __builtin_amdgcn_readfirstlane(threadIdx.x >> 6);  // 0..9 unit group
  const int word = blockIdx.x*64 + lane;
  const int dir  = blockIdx.y;
  const float4* __restrict__ P4d = P4 + dir*5000 + g5*5;              // 5 units of this group
  const unsigned int* __restrict__ W2d = W2 + dir*5000 + g5*500;      // uniform base
  const int* __restrict__ cptr = char_ids + word*16;

  // rows of 54 ushorts (108 B): uint view keeps the conflict-free stride-27 pattern
  __shared__ unsigned short hbuf[2][64*54];

  float c[5], hval[5];
  #pragma unroll
  for (int u = 0; u < 5; u++){ c[u] = 0.f; hval[u] = 0.f; }
  unsigned int* hz = (unsigned int*)hbuf[0];
  for (int i = threadIdx.x; i < 64*27; i += 640) hz[i] = 0u;
  __syncthreads();

  int cid = cptr[dir ? 15 : 0];
  #pragma unroll 1
  for (int t = 0; t < 16; t++){
    const int p = t & 1;
    float4 pg[5];
    #pragma unroll
    for (int u = 0; u < 5; u++) pg[u] = P4d[cid*50 + u];
    if (t < 15) cid = cptr[dir ? (14 - t) : (t + 1)];   // prefetch next step's id
    unsigned int hp[25];
    const unsigned int* hrow = (const unsigned int*)&hbuf[p][lane*54];
    #pragma unroll
    for (int k = 0; k < 25; k++) hp[k] = hrow[k];
    #pragma unroll
    for (int u = 0; u < 5; u++){
      const unsigned int* __restrict__ wr = W2d + u*100;
      float ai = pg[u].x, af = pg[u].y, ag = pg[u].z, ao = pg[u].w;
      #pragma unroll
      for (int k = 0; k < 25; k++){
        ai = dot2f(wr[k],      hp[k], ai);
        af = dot2f(wr[25 + k], hp[k], af);
        ag = dot2f(wr[50 + k], hp[k], ag);
        ao = dot2f(wr[75 + k], hp[k], ao);
      }
      c[u] = sigf(af)*c[u] + sigf(ai)*tanhf_(ag);
      hval[u] = sigf(ao)*tanhf_(c[u]);
    }
    #pragma unroll
    for (int i = 0; i < 5; i++)
      hbuf[1-p][lane*54 + g5*5 + i] = __half_as_ushort(__float2half(hval[i]));
    __syncthreads();
  }

  // coalesced epilogue: stage f32 h (full precision) in dead hbuf, write dense runs
  float* fst = (float*)hbuf;                 // 64*50 floats = 12800 B <= 13824 B
  #pragma unroll
  for (int i = 0; i < 5; i++) fst[lane*50 + g5*5 + i] = hval[i];
  __syncthreads();
  for (int idx = threadIdx.x; idx < 3200; idx += 640){
    int w = idx / 50; int j = idx - w*50;
    combined[(long)(blockIdx.x*64 + w)*396 + 296 + dir*50 + j] = fst[idx];
  }
}

// fuse MLP (unchanged)
__global__ __launch_bounds__(256) void k_fuse(const float* __restrict__ combined,
                                              const float* __restrict__ wFT,   // [396][200]
                                              const float* __restrict__ fb,
                                              float* __restrict__ fused){
  int tid = threadIdx.x; int base = blockIdx.x*4;
  __shared__ float rows[4*396];
  for (int idx = tid; idx < 4*396; idx += 256) rows[idx] = combined[(long)base*396 + idx];
  __syncthreads();
  if (tid < 200){
    float a0=0.f, a1=0.f, a2=0.f, a3=0.f;
    #pragma unroll 4
    for (int k = 0; k < 396; k++){
      float w = wFT[k*200 + tid];
      a0 += w*rows[k]; a1 += w*rows[396+k]; a2 += w*rows[792+k]; a3 += w*rows[1188+k];
    }
    float bb = fb[tid];
    fused[(base+0)*200 + tid] = fmaxf(a0 + bb, 0.f);
    fused[(base+1)*200 + tid] = fmaxf(a1 + bb, 0.f);
    fused[(base+2)*200 + tid] = fmaxf(a2 + bb, 0.f);
    fused[(base+3)*200 + tid] = fmaxf(a3 + bb, 0.f);
  }
}

// ---------------- context LSTM: hoisted x-projection ----------------
// Gx[dir][tok][512] (f16) = biasc + fused@wihT. Fully parallel over tokens.
__global__ __launch_bounds__(512) void k_gx(const float* __restrict__ fused,
                                            const unsigned int* __restrict__ wihP, // [2][100][512]
                                            const float* __restrict__ biasc,
                                            __half* __restrict__ Gx){
  const int dir = blockIdx.y, j = threadIdx.x;
  const int base = blockIdx.x*8;
  __shared__ __align__(16) unsigned int xh[8*100];
  for (int idx = j; idx < 800; idx += 512){
    int r = idx / 100, k = idx - r*100;
    const float2* fr2 = (const float2*)(fused + (long)(base + r)*200);
    float2 v = fr2[k];
    xh[r*100 + k] = packh2(v.x, v.y);
  }
  __syncthreads();
  float acc[8];
  float bj = biasc[dir*512 + j];
  #pragma unroll
  for (int r = 0; r < 8; r++) acc[r] = bj;
  const unsigned int* wp = wihP + dir*(100*512) + j;
  #pragma unroll 1
  for (int kk = 0; kk < 25; kk++){
    unsigned int w0 = wp[(4*kk+0)*512];
    unsigned int w1 = wp[(4*kk+1)*512];
    unsigned int w2 = wp[(4*kk+2)*512];
    unsigned int w3 = wp[(4*kk+3)*512];
    #pragma unroll
    for (int r = 0; r < 8; r++){
      uint4 xv = *(const uint4*)&xh[r*100 + kk*4];
      float a = acc[r];
      a = dot2f(w0, xv.x, a);
      a = dot2f(w1, xv.y, a);
      a = dot2f(w2, xv.z, a);
      a = dot2f(w3, xv.w, a);
      acc[r] = a;
    }
  }
  #pragma unroll
  for (int r = 0; r < 8; r++)
    Gx[((long)dir*16384 + base + r)*512 + j] = __float2half(acc[r]);
}

// recurrence-only context LSTM (unchanged)
__global__ __launch_bounds__(512) void k_ctx_rec(const __half* __restrict__ Gx,
                                                 const uint4* __restrict__ whhQ, // [2][16][512]
                                                 __half* __restrict__ H){
  const int b = blockIdx.x, dir = blockIdx.y, j = threadIdx.x;
  __shared__ __align__(16) unsigned int hh[64];
  __shared__ float gs[512];
  float c = 0.f;
  if (j < 64) hh[j] = 0u;
  __syncthreads();
  const __half* gx_base = Gx + ((long)dir*16384 + b*256)*512;
  const uint4* wq = whhQ + dir*(16*512) + j;

  #pragma unroll 1
  for (int t = 0; t < 256; t++){
    int tsrc = dir ? (255 - t) : t;
    float acc = __half2float(gx_base[(long)tsrc*512 + j]);
    const uint4* hq = (const uint4*)hh;
    #pragma unroll
    for (int k4 = 0; k4 < 16; k4++){
      uint4 w = wq[k4*512];
      uint4 hv = hq[k4];
      acc = dot2f(w.x, hv.x, acc);
      acc = dot2f(w.y, hv.y, acc);
      acc = dot2f(w.z, hv.z, acc);
      acc = dot2f(w.w, hv.w, acc);
    }
    gs[j] = acc;
    __syncthreads();
    if (j < 128){
      float gi = gs[j], gf = gs[j+128], gg = gs[j+256], go = gs[j+384];
      c = sigf(gf)*c + sigf(gi)*tanhf_(gg);
      float hv = sigf(go)*tanhf_(c);
      H[((long)b*256 + tsrc)*256 + dir*128 + j] = __float2half(hv);
      ((unsigned short*)hh)[j] = __half_as_ushort(__float2half(hv));
    }
    __syncthreads();
  }
}

// ---------------- attention + emissions (H is f16 now) ----------------

__global__ __launch_bounds__(256) void k_attn(const __half* __restrict__ H,
                                              const float* __restrict__ attnT,
                                              const float* __restrict__ attn_b,
                                              const float* __restrict__ attn_v,
                                              float* __restrict__ scores){
  int tid = threadIdx.x; int base = blockIdx.x*4;
  __shared__ float rows[4*256];
  __shared__ float red[4*256];
  for (int idx = tid; idx < 1024; idx += 256) rows[idx] = __half2float(H[(long)base*256 + idx]);
  __syncthreads();
  float a0=0.f, a1=0.f, a2=0.f, a3=0.f;
  #pragma unroll 4
  for (int k = 0; k < 256; k++){
    float w = attnT[k*256 + tid];
    a0 += w*rows[k]; a1 += w*rows[256+k]; a2 += w*rows[512+k]; a3 += w*rows[768+k];
  }
  float ab = attn_b[tid], av = attn_v[tid];
  red[tid]       = tanhf_(a0 + ab)*av;
  red[256 + tid] = tanhf_(a1 + ab)*av;
  red[512 + tid] = tanhf_(a2 + ab)*av;
  red[768 + tid] = tanhf_(a3 + ab)*av;
  __syncthreads();
  for (int s = 128; s > 0; s >>= 1){
    if (tid < s){
      red[tid] += red[tid+s]; red[256+tid] += red[256+tid+s];
      red[512+tid] += red[512+tid+s]; red[768+tid] += red[768+tid+s];
    }
    __syncthreads();
  }
  if (tid < 4) scores[base + tid] = red[tid*256];
}

__global__ __launch_bounds__(256) void k_softmax(float* __restrict__ scores){
  int b = blockIdx.x, tid = threadIdx.x;
  __shared__ float red[256];
  float s = scores[b*256 + tid];
  red[tid] = s; __syncthreads();
  for (int st = 128; st > 0; st >>= 1){ if (tid < st) red[tid] = fmaxf(red[tid], red[tid+st]); __syncthreads(); }
  float m = red[0]; __syncthreads();
  float e = __expf(s - m);
  red[tid] = e; __syncthreads();
  for (int st = 128; st > 0; st >>= 1){ if (tid < st) red[tid] += red[tid+st]; __syncthreads(); }
  float inv = 1.0f / red[0];
  scores[b*256 + tid] = e * inv;
}

__global__ __launch_bounds__(256) void k_emis(const __half* __restrict__ H, const float* __restrict__ scores,
                                              const float* __restrict__ emis_w, const float* __restrict__ emis_b,
                                              float* __restrict__ emis){
  int tid = threadIdx.x; int base = blockIdx.x*4;
  int r = tid >> 6, j = tid & 63;
  __shared__ float rows[4*256];
  for (int idx = tid; idx < 1024; idx += 256) rows[idx] = __half2float(H[(long)base*256 + idx]);
  __syncthreads();
  if (j < 9){
    float acc = 0.f;
    #pragma unroll 4
    for (int k = 0; k < 256; k++) acc += rows[r*256 + k] * emis_w[j*256 + k];
    int tok = base + r;
    emis[tok*9 + j] = scores[tok]*acc + emis_b[j];
  }
}

// ---------------- CRF ----------------

__global__ __launch_bounds__(64) void k_crf(const float* __restrict__ emis, const float* __restrict__ trans,
                                            const float* __restrict__ startv, const float* __restrict__ endv,
                                            float* __restrict__ logZ){
  int b = blockIdx.x; int j = threadIdx.x;
  bool act = (j < 9);
  float alpha = act ? (startv[j] + emis[(b*256)*9 + j]) : -1e30f;
  float trow[9];
  #pragma unroll
  for (int i = 0; i < 9; i++) trow[i] = act ? trans[i*9 + j] : 0.f;
  for (int t = 1; t < 256; t++){
    float v[9];
    #pragma unroll
    for (int i = 0; i < 9; i++) v[i] = __shfl(alpha, i) + trow[i];
    float m = v[0];
    #pragma unroll
    for (int i = 1; i < 9; i++) m = fmaxf(m, v[i]);
    float ssum = 0.f;
    #pragma unroll
    for (int i = 0; i < 9; i++) ssum += expf(v[i] - m);
    float e = act ? emis[(b*256 + t)*9 + j] : 0.f;
    alpha = m + logf(ssum) + e;
  }
  float v = act ? (alpha + endv[j]) : -1e30f;
  float vv[9];
  float m = -1e30f;
  #pragma unroll
  for (int i = 0; i < 9; i++){ vv[i] = __shfl(v, i); m = fmaxf(m, vv[i]); }
  float ssum = 0.f;
  #pragma unroll
  for (int i = 0; i < 9; i++) ssum += expf(vv[i] - m);
  if (j == 0) logZ[b] = m + logf(ssum);
}

__global__ __launch_bounds__(256) void k_num(const int* __restrict__ tags, const float* __restrict__ emis,
                                             const float* __restrict__ trans, const float* __restrict__ startv,
                                             const float* __restrict__ endv, float* __restrict__ num){
  int b = blockIdx.x, t = threadIdx.x;
  int tg = tags[b*256 + t];
  float v = emis[(b*256 + t)*9 + tg];
  if (t > 0) v += trans[tags[b*256 + t - 1]*9 + tg];
  __shared__ float red[256];
  red[t] = v; __syncthreads();
  for (int s = 128; s > 0; s >>= 1){ if (t < s) red[t] += red[t+s]; __syncthreads(); }
  if (t == 0) num[b] = red[0] + startv[tags[b*256]] + endv[tags[b*256 + 255]];
}

__global__ __launch_bounds__(64) void k_final(const float* __restrict__ logZ, const float* __restrict__ num,
                                              float* __restrict__ out){
  int b = threadIdx.x;
  float v = logZ[b] - num[b];
  for (int s = 32; s > 0; s >>= 1) v += __shfl_down(v, s);
  if (b == 0) out[0] = v * (1.0f/64.0f);
}

__global__ void k_diag(float* __restrict__ out, float ws_mb){
  if (threadIdx.x == 0) out[0] = -ws_mb;
}

// ---------------- launcher ----------------

extern "C" void kernel_launch(void* const* d_in, const int* in_sizes, int n_in,
                              void* d_out, int out_size, void* d_ws, size_t ws_size,
                              hipStream_t stream) {
  const int*   word_ids   = (const int*)  d_in[0];
  const int*   char_ids   = (const int*)  d_in[1];
  const int*   tags       = (const int*)  d_in[3];
  const float* word_emb   = (const float*)d_in[4];
  const float* emb_cnn    = (const float*)d_in[5];
  const float* conv_w3    = (const float*)d_in[6];
  const float* conv_b3    = (const float*)d_in[7];
  const float* conv_w5    = (const float*)d_in[8];
  const float* conv_b5    = (const float*)d_in[9];
  const float* conv_w7    = (const float*)d_in[10];
  const float* conv_b7    = (const float*)d_in[11];
  const float* emb_lstm   = (const float*)d_in[12];
  const float* cl_wih_f   = (const float*)d_in[13];
  const float* cl_whh_f   = (const float*)d_in[14];
  const float* cl_bih_f   = (const float*)d_in[15];
  const float* cl_bhh_f   = (const float*)d_in[16];
  const float* cl_wih_b   = (const float*)d_in[17];
  const float* cl_whh_b   = (const float*)d_in[18];
  const float* cl_bih_b   = (const float*)d_in[19];
  const float* cl_bhh_b   = (const float*)d_in[20];
  const float* fuse_w     = (const float*)d_in[21];
  const float* fuse_b     = (const float*)d_in[22];
  const float* ctx_wih_f  = (const float*)d_in[23];
  const float* ctx_whh_f  = (const float*)d_in[24];
  const float* ctx_bih_f  = (const float*)d_in[25];
  const float* ctx_bhh_f  = (const float*)d_in[26];
  const float* ctx_wih_b  = (const float*)d_in[27];
  const float* ctx_whh_b  = (const float*)d_in[28];
  const float* ctx_bih_b  = (const float*)d_in[29];
  const float* ctx_bhh_b  = (const float*)d_in[30];
  const float* attn_w     = (const float*)d_in[31];
  const float* attn_b     = (const float*)d_in[32];
  const float* attn_v     = (const float*)d_in[33];
  const float* emis_w     = (const float*)d_in[34];
  const float* emis_b     = (const float*)d_in[35];
  const float* crf_start  = (const float*)d_in[36];
  const float* crf_end    = (const float*)d_in[37];
  const float* crf_trans  = (const float*)d_in[38];
  float* out = (float*)d_out;
  float* ws  = (float*)d_ws;

  // workspace layout (float slots):
  const size_t OFF_A      = 0;          // 8388608
  const size_t OFF_FUSED  = 8388608;    // 3276800 (H f16 aliases this later)
  const size_t OFF_SCORES = 11665408;   // 16384
  const size_t OFF_EMIS   = 11681792;   // 147456
  const size_t OFF_WIHP   = 11829248;   // 102400
  const size_t OFF_WHHQ   = 11931648;   // 65536
  const size_t OFF_BIASC  = 11997184;   // 1024
  const size_t OFF_P4     = 11998208;   // 40000
  const size_t OFF_Q      = 12038208;   // 48000
  const size_t OFF_W2     = 12086208;   // 10000
  const size_t OFF_WFT    = 12096208;   // 79200
  const size_t OFF_ATTNT  = 12175408;   // 65536
  const size_t OFF_NUM    = 12240944;   // 64
  const size_t OFF_LOGZ   = 12241008;   // 64
  const size_t TOTAL_FLOATS = 12241072; // 48,964,288 bytes (~48.97 MB)

  if (ws_size < TOTAL_FLOATS * sizeof(float)) {
    k_diag<<<1, 64, 0, stream>>>(out, (float)((double)ws_size / (1024.0*1024.0)));
    return;
  }

  float* combined = ws + OFF_A;
  __half* Gx      = (__half*)(ws + OFF_A);
  float* fused    = ws + OFF_FUSED;
  __half* H       = (__half*)(ws + OFF_FUSED);
  float* scores   = ws + OFF_SCORES;
  float* emis     = ws + OFF_EMIS;
  unsigned int* wihP = (unsigned int*)(ws + OFF_WIHP);
  unsigned int* whhQ = (unsigned int*)(ws + OFF_WHHQ);
  float* biasc    = ws + OFF_BIASC;
  float4* P4      = (float4*)(ws + OFF_P4);
  float* Q        = ws + OFF_Q;
  unsigned int* W2 = (unsigned int*)(ws + OFF_W2);
  float* wFT      = ws + OFF_WFT;
  float* attnT    = ws + OFF_ATTNT;
  float* num      = ws + OFF_NUM;
  float* logZ     = ws + OFF_LOGZ;

  // prep
  k_transpose<<<(200*396 + 255)/256, 256, 0, stream>>>(fuse_w, wFT, 200, 396);
  k_transpose<<<(256*256 + 255)/256, 256, 0, stream>>>(attn_w, attnT, 256, 256);
  k_prep_ctx<<<(2*100*512 + 2*16*512*4 + 1024 + 255)/256, 256, 0, stream>>>(
      ctx_wih_f, ctx_whh_f, ctx_bih_f, ctx_bhh_f,
      ctx_wih_b, ctx_whh_b, ctx_bih_b, ctx_bhh_b, wihP, whhQ, biasc);
  k_prep_P4<<<(10000 + 255)/256, 256, 0, stream>>>(
      emb_lstm, cl_wih_f, cl_bih_f, cl_bhh_f, cl_wih_b, cl_bih_b, cl_bhh_b, P4);
  k_prep_whh2<<<(10000 + 255)/256, 256, 0, stream>>>(cl_whh_f, cl_whh_b, W2);
  k_prep_Q<<<(48000 + 255)/256, 256, 0, stream>>>(emb_cnn, conv_w3, conv_w5, conv_w7, Q);

  // features
  k_gather<<<(NB_B*NT*200 + 255)/256, 256, 0, stream>>>(word_ids, word_emb, combined);
  k_cnn2<3><<<NB_B*NT/16, 512, 0, stream>>>(char_ids, Q,         conv_b3, combined, 0);
  k_cnn2<5><<<NB_B*NT/16, 512, 0, stream>>>(char_ids, Q + 9600,  conv_b5, combined, 32);
  k_cnn2<7><<<NB_B*NT/16, 512, 0, stream>>>(char_ids, Q + 25600, conv_b7, combined, 64);
  k_char_lstm<<<dim3(NB_B*NT/64, 2), 640, 0, stream>>>(char_ids, P4, W2, combined);
  k_fuse<<<NB_B*NT/4, 256, 0, stream>>>(combined, wFT, fuse_b, fused);

  // context LSTM: parallel x-projection (Gx overwrites dead combined),
  // then recurrence-only kernel (H f16 overwrites dead fused)
  k_gx<<<dim3(NB_B*NT/8, 2), 512, 0, stream>>>(fused, wihP, biasc, Gx);
  k_ctx_rec<<<dim3(NB_B, 2), 512, 0, stream>>>(Gx, (const uint4*)whhQ, H);

  // attention + emissions
  k_attn<<<NB_B*NT/4, 256, 0, stream>>>(H, attnT, attn_b, attn_v, scores);
  k_softmax<<<NB_B, 256, 0, stream>>>(scores);
  k_emis<<<NB_B*NT/4, 256, 0, stream>>>(H, scores, emis_w, emis_b, emis);

  // CRF
  k_crf<<<NB_B, 64, 0, stream>>>(emis, crf_trans, crf_start, crf_end, logZ);
  k_num<<<NB_B, 256, 0, stream>>>(tags, emis, crf_trans, crf_start, crf_end, num);
  k_final<<<1, 64, 0, stream>>>(logZ, num, out);
}

// Round 4
// 1100.992 us; speedup vs baseline: 1.0098x; 1.0098x over previous
//
#include <hip/hip_runtime.h>
#include <hip/hip_fp16.h>

// Problem constants: B=64, T=256, Wc=16, V=100000, Cv=100, K=9
#define NB_B 64
#define NT 256
#define NWC 16

__device__ __forceinline__ float sigf(float x){ return 1.0f/(1.0f + __expf(-x)); }
__device__ __forceinline__ float tanhf_(float x){ return 1.0f - 2.0f/(__expf(2.0f*x)+1.0f); }

typedef _Float16 h2_t __attribute__((ext_vector_type(2)));

__device__ __forceinline__ float dot2f(unsigned int w, unsigned int x, float acc){
#if __has_builtin(__builtin_amdgcn_fdot2)
  return __builtin_amdgcn_fdot2(__builtin_bit_cast(h2_t, w), __builtin_bit_cast(h2_t, x), acc, false);
#else
  h2_t a = __builtin_bit_cast(h2_t, w), b = __builtin_bit_cast(h2_t, x);
  return acc + (float)a[0]*(float)b[0] + (float)a[1]*(float)b[1];
#endif
}

__device__ __forceinline__ unsigned int packh2(float a, float b){
  return ((unsigned int)__half_as_ushort(__float2half(a))) |
         (((unsigned int)__half_as_ushort(__float2half(b))) << 16);
}

// ---------------- prep kernels ----------------

__global__ void k_transpose(const float* __restrict__ src, float* __restrict__ dst, int R, int C){
  int idx = blockIdx.x*256 + threadIdx.x;
  if (idx < R*C){ int r = idx / C, c = idx % C; dst[c*R + r] = src[idx]; }
}

// ctx weights: wihP k-major [dir][k(0..99)][j] (coalesced for k_gx);
// whhQ k4-major uint4 [dir][k4(0..15)][j][4] (coalesced dwordx4 for k_ctx_rec);
// biasc[dir][j] fp32 (consumed by k_gx).
__global__ void k_prep_ctx(const float* __restrict__ wih_f, const float* __restrict__ whh_f,
                           const float* __restrict__ bih_f, const float* __restrict__ bhh_f,
                           const float* __restrict__ wih_b, const float* __restrict__ whh_b,
                           const float* __restrict__ bih_b, const float* __restrict__ bhh_b,
                           unsigned int* __restrict__ wihP, unsigned int* __restrict__ whhQ,
                           float* __restrict__ biasc){
  int idx = blockIdx.x*256 + threadIdx.x;
  const int NIH = 2*100*512, NHH = 2*16*512*4;
  if (idx < NIH){
    int dir = idx / (100*512); int r = idx % (100*512); int k = r >> 9; int j = r & 511;
    const float* wih = dir ? wih_b : wih_f;
    wihP[idx] = packh2(wih[j*200 + 2*k], wih[j*200 + 2*k + 1]);
  } else if (idx < NIH + NHH){
    int i2 = idx - NIH;
    int dir = i2 / 32768; int r = i2 % 32768;
    int k4 = r / 2048; int r2 = r % 2048; int j = r2 >> 2; int e = r2 & 3;
    const float* whh = dir ? whh_b : whh_f;
    whhQ[i2] = packh2(whh[j*128 + 8*k4 + 2*e], whh[j*128 + 8*k4 + 2*e + 1]);
  } else if (idx < NIH + NHH + 1024){
    int i2 = idx - NIH - NHH; int dir = i2 >> 9; int j = i2 & 511;
    biasc[i2] = dir ? (bih_b[j] + bhh_b[j]) : (bih_f[j] + bhh_f[j]);
  }
}

// char-LSTM x-projection table, gate-packed fp32
__global__ void k_prep_P4(const float* __restrict__ emb,
                          const float* __restrict__ wih_f, const float* __restrict__ bih_f, const float* __restrict__ bhh_f,
                          const float* __restrict__ wih_b, const float* __restrict__ bih_b, const float* __restrict__ bhh_b,
                          float4* __restrict__ P4){
  int idx = blockIdx.x*256 + threadIdx.x;
  if (idx >= 10000) return;               // 2 * 100 * 50
  int dir = idx / 5000; int r = idx % 5000; int c = r / 50; int u = r % 50;
  const float* wih = dir ? wih_b : wih_f;
  const float* bih = dir ? bih_b : bih_f;
  const float* bhh = dir ? bhh_b : bhh_f;
  float g4[4];
  #pragma unroll
  for (int gt = 0; gt < 4; gt++){
    int j = gt*50 + u;
    float acc = bih[j] + bhh[j];
    for (int k = 0; k < 30; k++) acc += emb[c*30 + k] * wih[j*30 + k];
    g4[gt] = acc;
  }
  P4[idx] = make_float4(g4[0], g4[1], g4[2], g4[3]);
}

// char-LSTM recurrent weights (R8/v2 layout): W2[dir][u][gate][k(0..24)]
__global__ void k_prep_whh2(const float* __restrict__ whh_f, const float* __restrict__ whh_b,
                            unsigned int* __restrict__ W2){
  int idx = blockIdx.x*256 + threadIdx.x;
  if (idx >= 10000) return;               // 2 * 50 * 4 * 25
  int dir = idx / 5000; int r = idx % 5000;
  int u = r / 100; int r2 = r % 100; int gt = r2 / 25; int k = r2 % 25;
  const float* whh = dir ? whh_b : whh_f;
  int j = gt*50 + u;
  W2[idx] = packh2(whh[j*50 + 2*k], whh[j*50 + 2*k + 1]);
}

// char-CNN lookup tables
__global__ void k_prep_Q(const float* __restrict__ emb, const float* __restrict__ w3,
                         const float* __restrict__ w5, const float* __restrict__ w7,
                         float* __restrict__ Q){
  int idx = blockIdx.x*256 + threadIdx.x;
  if (idx >= 48000) return;
  const float* w; int ks, r;
  if (idx < 9600){ w = w3; ks = 3; r = idx; }
  else if (idx < 25600){ w = w5; ks = 5; r = idx - 9600; }
  else { w = w7; ks = 7; r = idx - 25600; }
  int t = r / 3200; int o = (r / 100) % 32; int c = r % 100;
  float acc = 0.f;
  for (int i = 0; i < 30; i++) acc += emb[c*30 + i] * w[(o*30 + i)*ks + t];
  Q[idx] = acc;
}

// ---------------- feature construction ----------------

__global__ void k_gather(const int* __restrict__ word_ids, const float* __restrict__ word_emb,
                         float* __restrict__ combined){
  int idx = blockIdx.x*256 + threadIdx.x;
  if (idx >= NB_B*NT*200) return;
  int bt = idx / 200; int k = idx - bt*200;
  combined[bt*396 + k] = word_emb[(long)word_ids[bt]*200 + k];
}

// char CNN v2 (kept from R9): lane = output channel, Q staged in LDS [t][c][o]
template<int KS>
__global__ __launch_bounds__(512) void k_cnn2(const int* __restrict__ char_ids,
                                              const float* __restrict__ Qg,
                                              const float* __restrict__ bias,
                                              float* __restrict__ combined,
                                              int outoff){
  constexpr int PAD = KS/2;
  const int tid = threadIdx.x;
  __shared__ float Qlds[KS*3200];
  for (int idx = tid; idx < KS*3200; idx += 512){
    int t = idx / 3200; int r = idx - t*3200; int cc = r >> 5; int oo = r & 31;
    Qlds[idx] = Qg[(t*32 + oo)*100 + cc];
  }
  __syncthreads();
  const int o    = tid & 31;
  const int word = blockIdx.x*16 + ((tid >> 6) << 1) + ((tid >> 5) & 1);
  int ch[16];
  #pragma unroll
  for (int p = 0; p < 16; p++) ch[p] = char_ids[word*16 + p];
  float m = -1e30f;
  #pragma unroll
  for (int p = 0; p < 16; p++){
    float acc = 0.f;
    #pragma unroll
    for (int t = 0; t < KS; t++){
      int pp = p + t - PAD;
      if (pp >= 0 && pp < 16) acc += Qlds[(t*100 + ch[pp])*32 + o];
    }
    m = fmaxf(m, acc);
  }
  combined[(long)word*396 + 200 + outoff + o] = fmaxf(m + bias[o], 0.f);
}

// char LSTM v5 (R13): R11 + software-pipelined P4 gather.
// R11 postmortem: spill traffic eliminated (WRITE 273->6.7 MB) but dur flat
// at ~272 us -> latency-bound, not issue-bound (inst count says ~46 us of
// issue). The per-step critical-path head is the 64-way-divergent P4 gather
// (all lanes read different cid*800B rows) consumed at the START of every
// gate chain, re-paid every step by every barrier-locked wave.
// Fix: gather for step t+1 issued during step t's compute (cid already
// prefetched one step ahead); consume previous step's registers. All arrays
// remain fully-unrolled/static-indexed (no scratch, rule #20). +20 VGPR
// for the in-flight tile, ~90 total < 128 cap at min-waves 4.
__global__ __launch_bounds__(640, 4) void k_char_lstm(const int* __restrict__ char_ids,
                                                      const float4* __restrict__ P4,
                                                      const unsigned int* __restrict__ W2,
                                                      float* __restrict__ combined){
  const int lane = threadIdx.x & 63;                                  // word in block
  const int g5   = __builtin_amdgcn_readfirstlane(threadIdx.x >> 6);  // 0..9 unit group
  const int word = blockIdx.x*64 + lane;
  const int dir  = blockIdx.y;
  const float4* __restrict__ P4d = P4 + dir*5000 + g5*5;              // 5 units of this group
  const unsigned int* __restrict__ W2d = W2 + dir*5000 + g5*500;      // uniform base
  const int* __restrict__ cptr = char_ids + word*16;

  // rows of 54 ushorts (108 B): uint view keeps the conflict-free stride-27 pattern
  __shared__ unsigned short hbuf[2][64*54];

  float c[5], hval[5];
  #pragma unroll
  for (int u = 0; u < 5; u++){ c[u] = 0.f; hval[u] = 0.f; }
  unsigned int* hz = (unsigned int*)hbuf[0];
  for (int i = threadIdx.x; i < 64*27; i += 640) hz[i] = 0u;
  __syncthreads();

  // pipeline prologue: pg for step 0 in flight; cid for step 1 ready
  int cid0 = cptr[dir ? 15 : 0];
  float4 pga[5];
  #pragma unroll
  for (int u = 0; u < 5; u++) pga[u] = P4d[cid0*50 + u];
  int cid_n = cptr[dir ? 14 : 1];                      // id for step 1

  #pragma unroll 1
  for (int t = 0; t < 16; t++){
    const int p = t & 1;
    // issue LDS reads of h(t-1)
    unsigned int hp[25];
    const unsigned int* hrow = (const unsigned int*)&hbuf[p][lane*54];
    #pragma unroll
    for (int k = 0; k < 25; k++) hp[k] = hrow[k];
    // issue next step's gather (latency hides under this step's compute);
    // at t=15 the prefetch target is clamped in-bounds and the values are dead
    float4 pgb[5];
    #pragma unroll
    for (int u = 0; u < 5; u++) pgb[u] = P4d[cid_n*50 + u];
    int t2 = (t + 2 < 15) ? (t + 2) : 15;              // clamped step-(t+2) index
    cid_n = cptr[dir ? (15 - t2) : t2];
    // compute with pga (fetched last iteration)
    #pragma unroll
    for (int u = 0; u < 5; u++){
      const unsigned int* __restrict__ wr = W2d + u*100;
      float ai = pga[u].x, af = pga[u].y, ag = pga[u].z, ao = pga[u].w;
      #pragma unroll
      for (int k = 0; k < 25; k++){
        ai = dot2f(wr[k],      hp[k], ai);
        af = dot2f(wr[25 + k], hp[k], af);
        ag = dot2f(wr[50 + k], hp[k], ag);
        ao = dot2f(wr[75 + k], hp[k], ao);
      }
      c[u] = sigf(af)*c[u] + sigf(ai)*tanhf_(ag);
      hval[u] = sigf(ao)*tanhf_(c[u]);
    }
    #pragma unroll
    for (int i = 0; i < 5; i++)
      hbuf[1-p][lane*54 + g5*5 + i] = __half_as_ushort(__float2half(hval[i]));
    // rotate pipeline registers
    #pragma unroll
    for (int u = 0; u < 5; u++) pga[u] = pgb[u];
    __syncthreads();
  }

  // coalesced epilogue: stage f32 h (full precision) in dead hbuf, write dense runs
  float* fst = (float*)hbuf;                 // 64*50 floats = 12800 B <= 13824 B
  #pragma unroll
  for (int i = 0; i < 5; i++) fst[lane*50 + g5*5 + i] = hval[i];
  __syncthreads();
  for (int idx = threadIdx.x; idx < 3200; idx += 640){
    int w = idx / 50; int j = idx - w*50;
    combined[(long)(blockIdx.x*64 + w)*396 + 296 + dir*50 + j] = fst[idx];
  }
}

// fuse MLP (unchanged)
__global__ __launch_bounds__(256) void k_fuse(const float* __restrict__ combined,
                                              const float* __restrict__ wFT,   // [396][200]
                                              const float* __restrict__ fb,
                                              float* __restrict__ fused){
  int tid = threadIdx.x; int base = blockIdx.x*4;
  __shared__ float rows[4*396];
  for (int idx = tid; idx < 4*396; idx += 256) rows[idx] = combined[(long)base*396 + idx];
  __syncthreads();
  if (tid < 200){
    float a0=0.f, a1=0.f, a2=0.f, a3=0.f;
    #pragma unroll 4
    for (int k = 0; k < 396; k++){
      float w = wFT[k*200 + tid];
      a0 += w*rows[k]; a1 += w*rows[396+k]; a2 += w*rows[792+k]; a3 += w*rows[1188+k];
    }
    float bb = fb[tid];
    fused[(base+0)*200 + tid] = fmaxf(a0 + bb, 0.f);
    fused[(base+1)*200 + tid] = fmaxf(a1 + bb, 0.f);
    fused[(base+2)*200 + tid] = fmaxf(a2 + bb, 0.f);
    fused[(base+3)*200 + tid] = fmaxf(a3 + bb, 0.f);
  }
}

// ---------------- context LSTM: hoisted x-projection ----------------
// Gx[dir][tok][512] (f16) = biasc + fused@wihT. Fully parallel over tokens.
__global__ __launch_bounds__(512) void k_gx(const float* __restrict__ fused,
                                            const unsigned int* __restrict__ wihP, // [2][100][512]
                                            const float* __restrict__ biasc,
                                            __half* __restrict__ Gx){
  const int dir = blockIdx.y, j = threadIdx.x;
  const int base = blockIdx.x*8;
  __shared__ __align__(16) unsigned int xh[8*100];
  for (int idx = j; idx < 800; idx += 512){
    int r = idx / 100, k = idx - r*100;
    const float2* fr2 = (const float2*)(fused + (long)(base + r)*200);
    float2 v = fr2[k];
    xh[r*100 + k] = packh2(v.x, v.y);
  }
  __syncthreads();
  float acc[8];
  float bj = biasc[dir*512 + j];
  #pragma unroll
  for (int r = 0; r < 8; r++) acc[r] = bj;
  const unsigned int* wp = wihP + dir*(100*512) + j;
  #pragma unroll 1
  for (int kk = 0; kk < 25; kk++){
    unsigned int w0 = wp[(4*kk+0)*512];
    unsigned int w1 = wp[(4*kk+1)*512];
    unsigned int w2 = wp[(4*kk+2)*512];
    unsigned int w3 = wp[(4*kk+3)*512];
    #pragma unroll
    for (int r = 0; r < 8; r++){
      uint4 xv = *(const uint4*)&xh[r*100 + kk*4];
      float a = acc[r];
      a = dot2f(w0, xv.x, a);
      a = dot2f(w1, xv.y, a);
      a = dot2f(w2, xv.z, a);
      a = dot2f(w3, xv.w, a);
      acc[r] = a;
    }
  }
  #pragma unroll
  for (int r = 0; r < 8; r++)
    Gx[((long)dir*16384 + base + r)*512 + j] = __float2half(acc[r]);
}

// recurrence-only context LSTM (unchanged)
__global__ __launch_bounds__(512) void k_ctx_rec(const __half* __restrict__ Gx,
                                                 const uint4* __restrict__ whhQ, // [2][16][512]
                                                 __half* __restrict__ H){
  const int b = blockIdx.x, dir = blockIdx.y, j = threadIdx.x;
  __shared__ __align__(16) unsigned int hh[64];
  __shared__ float gs[512];
  float c = 0.f;
  if (j < 64) hh[j] = 0u;
  __syncthreads();
  const __half* gx_base = Gx + ((long)dir*16384 + b*256)*512;
  const uint4* wq = whhQ + dir*(16*512) + j;

  #pragma unroll 1
  for (int t = 0; t < 256; t++){
    int tsrc = dir ? (255 - t) : t;
    float acc = __half2float(gx_base[(long)tsrc*512 + j]);
    const uint4* hq = (const uint4*)hh;
    #pragma unroll
    for (int k4 = 0; k4 < 16; k4++){
      uint4 w = wq[k4*512];
      uint4 hv = hq[k4];
      acc = dot2f(w.x, hv.x, acc);
      acc = dot2f(w.y, hv.y, acc);
      acc = dot2f(w.z, hv.z, acc);
      acc = dot2f(w.w, hv.w, acc);
    }
    gs[j] = acc;
    __syncthreads();
    if (j < 128){
      float gi = gs[j], gf = gs[j+128], gg = gs[j+256], go = gs[j+384];
      c = sigf(gf)*c + sigf(gi)*tanhf_(gg);
      float hv = sigf(go)*tanhf_(c);
      H[((long)b*256 + tsrc)*256 + dir*128 + j] = __float2half(hv);
      ((unsigned short*)hh)[j] = __half_as_ushort(__float2half(hv));
    }
    __syncthreads();
  }
}

// ---------------- attention + emissions (H is f16 now) ----------------

__global__ __launch_bounds__(256) void k_attn(const __half* __restrict__ H,
                                              const float* __restrict__ attnT,
                                              const float* __restrict__ attn_b,
                                              const float* __restrict__ attn_v,
                                              float* __restrict__ scores){
  int tid = threadIdx.x; int base = blockIdx.x*4;
  __shared__ float rows[4*256];
  __shared__ float red[4*256];
  for (int idx = tid; idx < 1024; idx += 256) rows[idx] = __half2float(H[(long)base*256 + idx]);
  __syncthreads();
  float a0=0.f, a1=0.f, a2=0.f, a3=0.f;
  #pragma unroll 4
  for (int k = 0; k < 256; k++){
    float w = attnT[k*256 + tid];
    a0 += w*rows[k]; a1 += w*rows[256+k]; a2 += w*rows[512+k]; a3 += w*rows[768+k];
  }
  float ab = attn_b[tid], av = attn_v[tid];
  red[tid]       = tanhf_(a0 + ab)*av;
  red[256 + tid] = tanhf_(a1 + ab)*av;
  red[512 + tid] = tanhf_(a2 + ab)*av;
  red[768 + tid] = tanhf_(a3 + ab)*av;
  __syncthreads();
  for (int s = 128; s > 0; s >>= 1){
    if (tid < s){
      red[tid] += red[tid+s]; red[256+tid] += red[256+tid+s];
      red[512+tid] += red[512+tid+s]; red[768+tid] += red[768+tid+s];
    }
    __syncthreads();
  }
  if (tid < 4) scores[base + tid] = red[tid*256];
}

__global__ __launch_bounds__(256) void k_softmax(float* __restrict__ scores){
  int b = blockIdx.x, tid = threadIdx.x;
  __shared__ float red[256];
  float s = scores[b*256 + tid];
  red[tid] = s; __syncthreads();
  for (int st = 128; st > 0; st >>= 1){ if (tid < st) red[tid] = fmaxf(red[tid], red[tid+st]); __syncthreads(); }
  float m = red[0]; __syncthreads();
  float e = __expf(s - m);
  red[tid] = e; __syncthreads();
  for (int st = 128; st > 0; st >>= 1){ if (tid < st) red[tid] += red[tid+st]; __syncthreads(); }
  float inv = 1.0f / red[0];
  scores[b*256 + tid] = e * inv;
}

__global__ __launch_bounds__(256) void k_emis(const __half* __restrict__ H, const float* __restrict__ scores,
                                              const float* __restrict__ emis_w, const float* __restrict__ emis_b,
                                              float* __restrict__ emis){
  int tid = threadIdx.x; int base = blockIdx.x*4;
  int r = tid >> 6, j = tid & 63;
  __shared__ float rows[4*256];
  for (int idx = tid; idx < 1024; idx += 256) rows[idx] = __half2float(H[(long)base*256 + idx]);
  __syncthreads();
  if (j < 9){
    float acc = 0.f;
    #pragma unroll 4
    for (int k = 0; k < 256; k++) acc += rows[r*256 + k] * emis_w[j*256 + k];
    int tok = base + r;
    emis[tok*9 + j] = scores[tok]*acc + emis_b[j];
  }
}

// ---------------- CRF ----------------

__global__ __launch_bounds__(64) void k_crf(const float* __restrict__ emis, const float* __restrict__ trans,
                                            const float* __restrict__ startv, const float* __restrict__ endv,
                                            float* __restrict__ logZ){
  int b = blockIdx.x; int j = threadIdx.x;
  bool act = (j < 9);
  float alpha = act ? (startv[j] + emis[(b*256)*9 + j]) : -1e30f;
  float trow[9];
  #pragma unroll
  for (int i = 0; i < 9; i++) trow[i] = act ? trans[i*9 + j] : 0.f;
  for (int t = 1; t < 256; t++){
    float v[9];
    #pragma unroll
    for (int i = 0; i < 9; i++) v[i] = __shfl(alpha, i) + trow[i];
    float m = v[0];
    #pragma unroll
    for (int i = 1; i < 9; i++) m = fmaxf(m, v[i]);
    float ssum = 0.f;
    #pragma unroll
    for (int i = 0; i < 9; i++) ssum += expf(v[i] - m);
    float e = act ? emis[(b*256 + t)*9 + j] : 0.f;
    alpha = m + logf(ssum) + e;
  }
  float v = act ? (alpha + endv[j]) : -1e30f;
  float vv[9];
  float m = -1e30f;
  #pragma unroll
  for (int i = 0; i < 9; i++){ vv[i] = __shfl(v, i); m = fmaxf(m, vv[i]); }
  float ssum = 0.f;
  #pragma unroll
  for (int i = 0; i < 9; i++) ssum += expf(vv[i] - m);
  if (j == 0) logZ[b] = m + logf(ssum);
}

__global__ __launch_bounds__(256) void k_num(const int* __restrict__ tags, const float* __restrict__ emis,
                                             const float* __restrict__ trans, const float* __restrict__ startv,
                                             const float* __restrict__ endv, float* __restrict__ num){
  int b = blockIdx.x, t = threadIdx.x;
  int tg = tags[b*256 + t];
  float v = emis[(b*256 + t)*9 + tg];
  if (t > 0) v += trans[tags[b*256 + t - 1]*9 + tg];
  __shared__ float red[256];
  red[t] = v; __syncthreads();
  for (int s = 128; s > 0; s >>= 1){ if (t < s) red[t] += red[t+s]; __syncthreads(); }
  if (t == 0) num[b] = red[0] + startv[tags[b*256]] + endv[tags[b*256 + 255]];
}

__global__ __launch_bounds__(64) void k_final(const float* __restrict__ logZ, const float* __restrict__ num,
                                              float* __restrict__ out){
  int b = threadIdx.x;
  float v = logZ[b] - num[b];
  for (int s = 32; s > 0; s >>= 1) v += __shfl_down(v, s);
  if (b == 0) out[0] = v * (1.0f/64.0f);
}

__global__ void k_diag(float* __restrict__ out, float ws_mb){
  if (threadIdx.x == 0) out[0] = -ws_mb;
}

// ---------------- launcher ----------------

extern "C" void kernel_launch(void* const* d_in, const int* in_sizes, int n_in,
                              void* d_out, int out_size, void* d_ws, size_t ws_size,
                              hipStream_t stream) {
  const int*   word_ids   = (const int*)  d_in[0];
  const int*   char_ids   = (const int*)  d_in[1];
  const int*   tags       = (const int*)  d_in[3];
  const float* word_emb   = (const float*)d_in[4];
  const float* emb_cnn    = (const float*)d_in[5];
  const float* conv_w3    = (const float*)d_in[6];
  const float* conv_b3    = (const float*)d_in[7];
  const float* conv_w5    = (const float*)d_in[8];
  const float* conv_b5    = (const float*)d_in[9];
  const float* conv_w7    = (const float*)d_in[10];
  const float* conv_b7    = (const float*)d_in[11];
  const float* emb_lstm   = (const float*)d_in[12];
  const float* cl_wih_f   = (const float*)d_in[13];
  const float* cl_whh_f   = (const float*)d_in[14];
  const float* cl_bih_f   = (const float*)d_in[15];
  const float* cl_bhh_f   = (const float*)d_in[16];
  const float* cl_wih_b   = (const float*)d_in[17];
  const float* cl_whh_b   = (const float*)d_in[18];
  const float* cl_bih_b   = (const float*)d_in[19];
  const float* cl_bhh_b   = (const float*)d_in[20];
  const float* fuse_w     = (const float*)d_in[21];
  const float* fuse_b     = (const float*)d_in[22];
  const float* ctx_wih_f  = (const float*)d_in[23];
  const float* ctx_whh_f  = (const float*)d_in[24];
  const float* ctx_bih_f  = (const float*)d_in[25];
  const float* ctx_bhh_f  = (const float*)d_in[26];
  const float* ctx_wih_b  = (const float*)d_in[27];
  const float* ctx_whh_b  = (const float*)d_in[28];
  const float* ctx_bih_b  = (const float*)d_in[29];
  const float* ctx_bhh_b  = (const float*)d_in[30];
  const float* attn_w     = (const float*)d_in[31];
  const float* attn_b     = (const float*)d_in[32];
  const float* attn_v     = (const float*)d_in[33];
  const float* emis_w     = (const float*)d_in[34];
  const float* emis_b     = (const float*)d_in[35];
  const float* crf_start  = (const float*)d_in[36];
  const float* crf_end    = (const float*)d_in[37];
  const float* crf_trans  = (const float*)d_in[38];
  float* out = (float*)d_out;
  float* ws  = (float*)d_ws;

  // workspace layout (float slots):
  const size_t OFF_A      = 0;          // 8388608
  const size_t OFF_FUSED  = 8388608;    // 3276800 (H f16 aliases this later)
  const size_t OFF_SCORES = 11665408;   // 16384
  const size_t OFF_EMIS   = 11681792;   // 147456
  const size_t OFF_WIHP   = 11829248;   // 102400
  const size_t OFF_WHHQ   = 11931648;   // 65536
  const size_t OFF_BIASC  = 11997184;   // 1024
  const size_t OFF_P4     = 11998208;   // 40000
  const size_t OFF_Q      = 12038208;   // 48000
  const size_t OFF_W2     = 12086208;   // 10000
  const size_t OFF_WFT    = 12096208;   // 79200
  const size_t OFF_ATTNT  = 12175408;   // 65536
  const size_t OFF_NUM    = 12240944;   // 64
  const size_t OFF_LOGZ   = 12241008;   // 64
  const size_t TOTAL_FLOATS = 12241072; // 48,964,288 bytes (~48.97 MB)

  if (ws_size < TOTAL_FLOATS * sizeof(float)) {
    k_diag<<<1, 64, 0, stream>>>(out, (float)((double)ws_size / (1024.0*1024.0)));
    return;
  }

  float* combined = ws + OFF_A;
  __half* Gx      = (__half*)(ws + OFF_A);
  float* fused    = ws + OFF_FUSED;
  __half* H       = (__half*)(ws + OFF_FUSED);
  float* scores   = ws + OFF_SCORES;
  float* emis     = ws + OFF_EMIS;
  unsigned int* wihP = (unsigned int*)(ws + OFF_WIHP);
  unsigned int* whhQ = (unsigned int*)(ws + OFF_WHHQ);
  float* biasc    = ws + OFF_BIASC;
  float4* P4      = (float4*)(ws + OFF_P4);
  float* Q        = ws + OFF_Q;
  unsigned int* W2 = (unsigned int*)(ws + OFF_W2);
  float* wFT      = ws + OFF_WFT;
  float* attnT    = ws + OFF_ATTNT;
  float* num      = ws + OFF_NUM;
  float* logZ     = ws + OFF_LOGZ;

  // prep
  k_transpose<<<(200*396 + 255)/256, 256, 0, stream>>>(fuse_w, wFT, 200, 396);
  k_transpose<<<(256*256 + 255)/256, 256, 0, stream>>>(attn_w, attnT, 256, 256);
  k_prep_ctx<<<(2*100*512 + 2*16*512*4 + 1024 + 255)/256, 256, 0, stream>>>(
      ctx_wih_f, ctx_whh_f, ctx_bih_f, ctx_bhh_f,
      ctx_wih_b, ctx_whh_b, ctx_bih_b, ctx_bhh_b, wihP, whhQ, biasc);
  k_prep_P4<<<(10000 + 255)/256, 256, 0, stream>>>(
      emb_lstm, cl_wih_f, cl_bih_f, cl_bhh_f, cl_wih_b, cl_bih_b, cl_bhh_b, P4);
  k_prep_whh2<<<(10000 + 255)/256, 256, 0, stream>>>(cl_whh_f, cl_whh_b, W2);
  k_prep_Q<<<(48000 + 255)/256, 256, 0, stream>>>(emb_cnn, conv_w3, conv_w5, conv_w7, Q);

  // features
  k_gather<<<(NB_B*NT*200 + 255)/256, 256, 0, stream>>>(word_ids, word_emb, combined);
  k_cnn2<3><<<NB_B*NT/16, 512, 0, stream>>>(char_ids, Q,         conv_b3, combined, 0);
  k_cnn2<5><<<NB_B*NT/16, 512, 0, stream>>>(char_ids, Q + 9600,  conv_b5, combined, 32);
  k_cnn2<7><<<NB_B*NT/16, 512, 0, stream>>>(char_ids, Q + 25600, conv_b7, combined, 64);
  k_char_lstm<<<dim3(NB_B*NT/64, 2), 640, 0, stream>>>(char_ids, P4, W2, combined);
  k_fuse<<<NB_B*NT/4, 256, 0, stream>>>(combined, wFT, fuse_b, fused);

  // context LSTM: parallel x-projection (Gx overwrites dead combined),
  // then recurrence-only kernel (H f16 overwrites dead fused)
  k_gx<<<dim3(NB_B*NT/8, 2), 512, 0, stream>>>(fused, wihP, biasc, Gx);
  k_ctx_rec<<<dim3(NB_B, 2), 512, 0, stream>>>(Gx, (const uint4*)whhQ, H);

  // attention + emissions
  k_attn<<<NB_B*NT/4, 256, 0, stream>>>(H, attnT, attn_b, attn_v, scores);
  k_softmax<<<NB_B, 256, 0, stream>>>(scores);
  k_emis<<<NB_B*NT/4, 256, 0, stream>>>(H, scores, emis_w, emis_b, emis);

  // CRF
  k_crf<<<NB_B, 64, 0, stream>>>(emis, crf_trans, crf_start, crf_end, logZ);
  k_num<<<NB_B, 256, 0, stream>>>(tags, emis, crf_trans, crf_start, crf_end, num);
  k_final<<<1, 64, 0, stream>>>(logZ, num, out);
}

// Round 5
// 929.050 us; speedup vs baseline: 1.1967x; 1.1851x over previous
//
#include <hip/hip_runtime.h>
#include <hip/hip_fp16.h>

// Problem constants: B=64, T=256, Wc=16, V=100000, Cv=100, K=9
#define NB_B 64
#define NT 256
#define NWC 16

__device__ __forceinline__ float sigf(float x){ return 1.0f/(1.0f + __expf(-x)); }
__device__ __forceinline__ float tanhf_(float x){ return 1.0f - 2.0f/(__expf(2.0f*x)+1.0f); }

typedef _Float16 h2_t __attribute__((ext_vector_type(2)));
typedef _Float16 f16x8 __attribute__((ext_vector_type(8)));
typedef float    f32x4 __attribute__((ext_vector_type(4)));

__device__ __forceinline__ float dot2f(unsigned int w, unsigned int x, float acc){
#if __has_builtin(__builtin_amdgcn_fdot2)
  return __builtin_amdgcn_fdot2(__builtin_bit_cast(h2_t, w), __builtin_bit_cast(h2_t, x), acc, false);
#else
  h2_t a = __builtin_bit_cast(h2_t, w), b = __builtin_bit_cast(h2_t, x);
  return acc + (float)a[0]*(float)b[0] + (float)a[1]*(float)b[1];
#endif
}

__device__ __forceinline__ unsigned int packh2(float a, float b){
  return ((unsigned int)__half_as_ushort(__float2half(a))) |
         (((unsigned int)__half_as_ushort(__float2half(b))) << 16);
}

// ---------------- prep kernels ----------------

__global__ void k_transpose(const float* __restrict__ src, float* __restrict__ dst, int R, int C){
  int idx = blockIdx.x*256 + threadIdx.x;
  if (idx < R*C){ int r = idx / C, c = idx % C; dst[c*R + r] = src[idx]; }
}

// ctx weights: wihP k-major [dir][k(0..99)][j] (coalesced for k_gx);
// whhQ k4-major uint4 [dir][k4(0..15)][j][4] (coalesced dwordx4 for k_ctx_rec);
// biasc[dir][j] fp32 (consumed by k_gx).
__global__ void k_prep_ctx(const float* __restrict__ wih_f, const float* __restrict__ whh_f,
                           const float* __restrict__ bih_f, const float* __restrict__ bhh_f,
                           const float* __restrict__ wih_b, const float* __restrict__ whh_b,
                           const float* __restrict__ bih_b, const float* __restrict__ bhh_b,
                           unsigned int* __restrict__ wihP, unsigned int* __restrict__ whhQ,
                           float* __restrict__ biasc){
  int idx = blockIdx.x*256 + threadIdx.x;
  const int NIH = 2*100*512, NHH = 2*16*512*4;
  if (idx < NIH){
    int dir = idx / (100*512); int r = idx % (100*512); int k = r >> 9; int j = r & 511;
    const float* wih = dir ? wih_b : wih_f;
    wihP[idx] = packh2(wih[j*200 + 2*k], wih[j*200 + 2*k + 1]);
  } else if (idx < NIH + NHH){
    int i2 = idx - NIH;
    int dir = i2 / 32768; int r = i2 % 32768;
    int k4 = r / 2048; int r2 = r % 2048; int j = r2 >> 2; int e = r2 & 3;
    const float* whh = dir ? whh_b : whh_f;
    whhQ[i2] = packh2(whh[j*128 + 8*k4 + 2*e], whh[j*128 + 8*k4 + 2*e + 1]);
  } else if (idx < NIH + NHH + 1024){
    int i2 = idx - NIH - NHH; int dir = i2 >> 9; int j = i2 & 511;
    biasc[i2] = dir ? (bih_b[j] + bhh_b[j]) : (bih_f[j] + bhh_f[j]);
  }
}

// char-LSTM x-projection table, MFMA-interleaved layout:
// P4I[dir][cid][n(0..207)], n = 4*u + gate (i,f,g,o), f32.
__global__ void k_prep_p4i(const float* __restrict__ emb,
                           const float* __restrict__ wih_f, const float* __restrict__ bih_f, const float* __restrict__ bhh_f,
                           const float* __restrict__ wih_b, const float* __restrict__ bih_b, const float* __restrict__ bhh_b,
                           float* __restrict__ P4I){
  int idx = blockIdx.x*256 + threadIdx.x;
  if (idx >= 41600) return;               // 2 * 100 * 208
  int n = idx % 208; int cd = idx / 208; int cid = cd % 100; int dir = cd / 100;
  int u = n >> 2, g = n & 3;
  float v = 0.f;
  if (u < 50){
    int j = g*50 + u;
    const float* wih = dir ? wih_b : wih_f;
    const float* bih = dir ? bih_b : bih_f;
    const float* bhh = dir ? bhh_b : bhh_f;
    float acc = bih[j] + bhh[j];
    for (int k = 0; k < 30; k++) acc += emb[cid*30 + k] * wih[j*30 + k];
    v = acc;
  }
  P4I[idx] = v;
}

// char-LSTM recurrent weights as MFMA B-fragments (f16):
// WB[dir][frag=tau*2+kh][lane(64)][e(8)], value = Whh[j = g*50+u][k],
// n = 16*tau + (lane&15) = 4u+g ; k = kh*32 + (lane>>4)*8 + e ; zero-padded.
// Only requirement: same (lane-group,reg)->k enumeration as the A-side h layout.
__global__ void k_prep_wb(const float* __restrict__ whh_f, const float* __restrict__ whh_b,
                          unsigned short* __restrict__ WB){
  int idx = blockIdx.x*256 + threadIdx.x;
  if (idx >= 26624) return;               // 2 * 26 * 64 * 8
  int e = idx & 7; int l = (idx >> 3) & 63;
  int dirf = idx >> 9;                     // dir*26 + frag
  int dir = dirf / 26; int fr = dirf % 26;
  int tau = fr >> 1, kh = fr & 1;
  int n = 16*tau + (l & 15);
  int u = n >> 2, g = n & 3;
  int k = kh*32 + (l >> 4)*8 + e;
  const float* whh = dir ? whh_b : whh_f;
  float v = (u < 50 && k < 50) ? whh[(g*50 + u)*50 + k] : 0.f;
  WB[idx] = __half_as_ushort(__float2half(v));
}

// char-CNN lookup tables
__global__ void k_prep_Q(const float* __restrict__ emb, const float* __restrict__ w3,
                         const float* __restrict__ w5, const float* __restrict__ w7,
                         float* __restrict__ Q){
  int idx = blockIdx.x*256 + threadIdx.x;
  if (idx >= 48000) return;
  const float* w; int ks, r;
  if (idx < 9600){ w = w3; ks = 3; r = idx; }
  else if (idx < 25600){ w = w5; ks = 5; r = idx - 9600; }
  else { w = w7; ks = 7; r = idx - 25600; }
  int t = r / 3200; int o = (r / 100) % 32; int c = r % 100;
  float acc = 0.f;
  for (int i = 0; i < 30; i++) acc += emb[c*30 + i] * w[(o*30 + i)*ks + t];
  Q[idx] = acc;
}

// ---------------- feature construction ----------------

__global__ void k_gather(const int* __restrict__ word_ids, const float* __restrict__ word_emb,
                         float* __restrict__ combined){
  int idx = blockIdx.x*256 + threadIdx.x;
  if (idx >= NB_B*NT*200) return;
  int bt = idx / 200; int k = idx - bt*200;
  combined[bt*396 + k] = word_emb[(long)word_ids[bt]*200 + k];
}

// char CNN v2 (kept from R9): lane = output channel, Q staged in LDS [t][c][o]
template<int KS>
__global__ __launch_bounds__(512) void k_cnn2(const int* __restrict__ char_ids,
                                              const float* __restrict__ Qg,
                                              const float* __restrict__ bias,
                                              float* __restrict__ combined,
                                              int outoff){
  constexpr int PAD = KS/2;
  const int tid = threadIdx.x;
  __shared__ float Qlds[KS*3200];
  for (int idx = tid; idx < KS*3200; idx += 512){
    int t = idx / 3200; int r = idx - t*3200; int cc = r >> 5; int oo = r & 31;
    Qlds[idx] = Qg[(t*32 + oo)*100 + cc];
  }
  __syncthreads();
  const int o    = tid & 31;
  const int word = blockIdx.x*16 + ((tid >> 6) << 1) + ((tid >> 5) & 1);
  int ch[16];
  #pragma unroll
  for (int p = 0; p < 16; p++) ch[p] = char_ids[word*16 + p];
  float m = -1e30f;
  #pragma unroll
  for (int p = 0; p < 16; p++){
    float acc = 0.f;
    #pragma unroll
    for (int t = 0; t < KS; t++){
      int pp = p + t - PAD;
      if (pp >= 0 && pp < 16) acc += Qlds[(t*100 + ch[pp])*32 + o];
    }
    m = fmaxf(m, acc);
  }
  combined[(long)word*396 + 200 + outoff + o] = fmaxf(m + bias[o], 0.f);
}

// char LSTM v6 (R14): MFMA rewrite. R10/R11/R13 all plateaued at 264-292 us:
// VGPR_Count=40 proves hipcc reschedules away source-level pipelining (m131-
// m141 lesson); the dot2f+scalar-weight-reload+barrier structure is the
// ceiling. New structure: per wave = 16 words; h@Whh^T via
// v_mfma_f32_16x16x32_f16 (same f16-in/f32-acc precision as dot2f path).
// K=50 padded to 64 (2 MFMAs), N=200 padded to 208 (13 tiles), gate order
// n=4u+g so a unit's i,f,g,o are one ds_read_b128. Weights = 26 B-frags
// resident in VGPRs for the whole kernel (no per-step weight reload).
// C-init = P4I gather (bias + x-proj, f32). Two N-phases keep LDS at 44KB.
// Wave-private LDS slices -> ZERO in-loop barriers (same-wave lgkmcnt only).
__global__ __launch_bounds__(256, 2) void k_char_lstm(const int* __restrict__ char_ids,
                                                      const float* __restrict__ P4I,
                                                      const unsigned short* __restrict__ WB,
                                                      float* __restrict__ combined){
  const int tid  = threadIdx.x;
  const int wv   = tid >> 6;            // wave 0..3 (uniform)
  const int lane = tid & 63;
  const int c15  = lane & 15;
  const int grp  = lane >> 4;           // 0..3
  const int dir  = blockIdx.y;
  const int wbase = blockIdx.x*64 + wv*16;

  __shared__ __align__(16) float          glds_all[4][16*124]; // gates f32, row pad 124
  __shared__ __align__(16) unsigned short hlds_all[4][16*72];  // h f16, row pad 72
  __shared__ int                          chl_all[4][16*16];   // char ids
  float*          glds = glds_all[wv];
  unsigned short* hlds = hlds_all[wv];
  int*            chl  = chl_all[wv];

  // ---- load the 26 weight B-fragments (resident all kernel) ----
  f16x8 bf[26];
  {
    const unsigned short* wb = WB + ((long)dir*26)*512 + lane*8;
    #pragma unroll
    for (int f = 0; f < 26; f++)
      bf[f] = *reinterpret_cast<const f16x8*>(wb + f*512);
  }

  // ---- stage chars, zero h (incl. k-padding cols 50..71) ----
  for (int i = lane; i < 256; i += 64){
    int w = i >> 4, t = i & 15;
    chl[i] = char_ids[(long)(wbase + w)*16 + t];
  }
  for (int i = lane; i < 16*72; i += 64) hlds[i] = 0;
  __syncthreads();   // once; in-loop deps are all same-wave

  float cc[13], hfin[13];
  #pragma unroll
  for (int q = 0; q < 13; q++){ cc[q] = 0.f; hfin[q] = 0.f; }

  const float* pbase = P4I + (long)dir*20800 + c15;   // 100*208

  #pragma unroll 1
  for (int t = 0; t < 16; t++){
    const int tt = dir ? (15 - t) : t;
    // cids for this lane's 4 C-rows (words grp*4+r) — broadcast LDS reads
    int cid0 = chl[(grp*4+0)*16 + tt];
    int cid1 = chl[(grp*4+1)*16 + tt];
    int cid2 = chl[(grp*4+2)*16 + tt];
    int cid3 = chl[(grp*4+3)*16 + tt];
    const float* p0 = pbase + cid0*208;
    const float* p1 = pbase + cid1*208;
    const float* p2 = pbase + cid2*208;
    const float* p3 = pbase + cid3*208;

    // A fragments: h(t-1), rows = words (lane&15), k = (lane>>4)*8+e (+32 for kh1)
    f16x8 a0 = *reinterpret_cast<const f16x8*>(&hlds[c15*72 + grp*8]);
    f16x8 a1 = *reinterpret_cast<const f16x8*>(&hlds[c15*72 + 32 + grp*8]);

    // ---- phase A: N-tiles 0..6 (units 0..27) ----
    {
      f32x4 acc[7];
      #pragma unroll
      for (int tau = 0; tau < 7; tau++){
        f32x4 ci;
        ci[0] = p0[16*tau]; ci[1] = p1[16*tau]; ci[2] = p2[16*tau]; ci[3] = p3[16*tau];
        f32x4 m0 = __builtin_amdgcn_mfma_f32_16x16x32_f16(a0, bf[2*tau+0], ci, 0, 0, 0);
        acc[tau]  = __builtin_amdgcn_mfma_f32_16x16x32_f16(a1, bf[2*tau+1], m0, 0, 0, 0);
      }
      #pragma unroll
      for (int tau = 0; tau < 7; tau++)
        #pragma unroll
        for (int r = 0; r < 4; r++)
          glds[(grp*4+r)*124 + tau*16 + c15] = acc[tau][r];
      #pragma unroll
      for (int q = 0; q < 7; q++){
        int u = grp*7 + q;
        f32x4 gq = *reinterpret_cast<const f32x4*>(&glds[c15*124 + 4*u]);
        float cn = sigf(gq[1])*cc[q] + sigf(gq[0])*tanhf_(gq[2]);
        cc[q] = cn;
        float hv = sigf(gq[3])*tanhf_(cn);
        hfin[q] = hv;
        hlds[c15*72 + u] = __half_as_ushort(__float2half(hv));
      }
    }
    // ---- phase B: N-tiles 7..12 (units 28..49) ----
    {
      f32x4 acc[6];
      #pragma unroll
      for (int s = 0; s < 6; s++){
        int tau = 7 + s;
        f32x4 ci;
        ci[0] = p0[16*tau]; ci[1] = p1[16*tau]; ci[2] = p2[16*tau]; ci[3] = p3[16*tau];
        f32x4 m0 = __builtin_amdgcn_mfma_f32_16x16x32_f16(a0, bf[2*tau+0], ci, 0, 0, 0);
        acc[s]    = __builtin_amdgcn_mfma_f32_16x16x32_f16(a1, bf[2*tau+1], m0, 0, 0, 0);
      }
      #pragma unroll
      for (int s = 0; s < 6; s++)
        #pragma unroll
        for (int r = 0; r < 4; r++)
          glds[(grp*4+r)*124 + s*16 + c15] = acc[s][r];
      #pragma unroll
      for (int q = 0; q < 6; q++){
        int u = 28 + grp*6 + q;
        if (u < 50){
          f32x4 gq = *reinterpret_cast<const f32x4*>(&glds[c15*124 + 4*u - 112]);
          float cn = sigf(gq[1])*cc[7+q] + sigf(gq[0])*tanhf_(gq[2]);
          cc[7+q] = cn;
          float hv = sigf(gq[3])*tanhf_(cn);
          hfin[7+q] = hv;
          hlds[c15*72 + u] = __half_as_ushort(__float2half(hv));
        }
      }
    }
  }

  // ---- epilogue: stage f32 h in dead glds as [16][50], coalesced copy out ----
  #pragma unroll
  for (int q = 0; q < 7; q++) glds[c15*50 + grp*7 + q] = hfin[q];
  #pragma unroll
  for (int q = 0; q < 6; q++){
    int u = 28 + grp*6 + q;
    if (u < 50) glds[c15*50 + u] = hfin[7+q];
  }
  __builtin_amdgcn_s_waitcnt(0);  // drain lds writes before cross-lane reads (same wave)
  for (int i = lane; i < 800; i += 64){
    int w = i / 50; int j = i - w*50;
    combined[(long)(wbase + w)*396 + 296 + dir*50 + j] = glds[i];
  }
}

// fuse MLP (unchanged)
__global__ __launch_bounds__(256) void k_fuse(const float* __restrict__ combined,
                                              const float* __restrict__ wFT,   // [396][200]
                                              const float* __restrict__ fb,
                                              float* __restrict__ fused){
  int tid = threadIdx.x; int base = blockIdx.x*4;
  __shared__ float rows[4*396];
  for (int idx = tid; idx < 4*396; idx += 256) rows[idx] = combined[(long)base*396 + idx];
  __syncthreads();
  if (tid < 200){
    float a0=0.f, a1=0.f, a2=0.f, a3=0.f;
    #pragma unroll 4
    for (int k = 0; k < 396; k++){
      float w = wFT[k*200 + tid];
      a0 += w*rows[k]; a1 += w*rows[396+k]; a2 += w*rows[792+k]; a3 += w*rows[1188+k];
    }
    float bb = fb[tid];
    fused[(base+0)*200 + tid] = fmaxf(a0 + bb, 0.f);
    fused[(base+1)*200 + tid] = fmaxf(a1 + bb, 0.f);
    fused[(base+2)*200 + tid] = fmaxf(a2 + bb, 0.f);
    fused[(base+3)*200 + tid] = fmaxf(a3 + bb, 0.f);
  }
}

// ---------------- context LSTM: hoisted x-projection ----------------
// Gx[dir][tok][512] (f16) = biasc + fused@wihT. Fully parallel over tokens.
__global__ __launch_bounds__(512) void k_gx(const float* __restrict__ fused,
                                            const unsigned int* __restrict__ wihP, // [2][100][512]
                                            const float* __restrict__ biasc,
                                            __half* __restrict__ Gx){
  const int dir = blockIdx.y, j = threadIdx.x;
  const int base = blockIdx.x*8;
  __shared__ __align__(16) unsigned int xh[8*100];
  for (int idx = j; idx < 800; idx += 512){
    int r = idx / 100, k = idx - r*100;
    const float2* fr2 = (const float2*)(fused + (long)(base + r)*200);
    float2 v = fr2[k];
    xh[r*100 + k] = packh2(v.x, v.y);
  }
  __syncthreads();
  float acc[8];
  float bj = biasc[dir*512 + j];
  #pragma unroll
  for (int r = 0; r < 8; r++) acc[r] = bj;
  const unsigned int* wp = wihP + dir*(100*512) + j;
  #pragma unroll 1
  for (int kk = 0; kk < 25; kk++){
    unsigned int w0 = wp[(4*kk+0)*512];
    unsigned int w1 = wp[(4*kk+1)*512];
    unsigned int w2 = wp[(4*kk+2)*512];
    unsigned int w3 = wp[(4*kk+3)*512];
    #pragma unroll
    for (int r = 0; r < 8; r++){
      uint4 xv = *(const uint4*)&xh[r*100 + kk*4];
      float a = acc[r];
      a = dot2f(w0, xv.x, a);
      a = dot2f(w1, xv.y, a);
      a = dot2f(w2, xv.z, a);
      a = dot2f(w3, xv.w, a);
      acc[r] = a;
    }
  }
  #pragma unroll
  for (int r = 0; r < 8; r++)
    Gx[((long)dir*16384 + base + r)*512 + j] = __float2half(acc[r]);
}

// recurrence-only context LSTM (unchanged)
__global__ __launch_bounds__(512) void k_ctx_rec(const __half* __restrict__ Gx,
                                                 const uint4* __restrict__ whhQ, // [2][16][512]
                                                 __half* __restrict__ H){
  const int b = blockIdx.x, dir = blockIdx.y, j = threadIdx.x;
  __shared__ __align__(16) unsigned int hh[64];
  __shared__ float gs[512];
  float c = 0.f;
  if (j < 64) hh[j] = 0u;
  __syncthreads();
  const __half* gx_base = Gx + ((long)dir*16384 + b*256)*512;
  const uint4* wq = whhQ + dir*(16*512) + j;

  #pragma unroll 1
  for (int t = 0; t < 256; t++){
    int tsrc = dir ? (255 - t) : t;
    float acc = __half2float(gx_base[(long)tsrc*512 + j]);
    const uint4* hq = (const uint4*)hh;
    #pragma unroll
    for (int k4 = 0; k4 < 16; k4++){
      uint4 w = wq[k4*512];
      uint4 hv = hq[k4];
      acc = dot2f(w.x, hv.x, acc);
      acc = dot2f(w.y, hv.y, acc);
      acc = dot2f(w.z, hv.z, acc);
      acc = dot2f(w.w, hv.w, acc);
    }
    gs[j] = acc;
    __syncthreads();
    if (j < 128){
      float gi = gs[j], gf = gs[j+128], gg = gs[j+256], go = gs[j+384];
      c = sigf(gf)*c + sigf(gi)*tanhf_(gg);
      float hv = sigf(go)*tanhf_(c);
      H[((long)b*256 + tsrc)*256 + dir*128 + j] = __float2half(hv);
      ((unsigned short*)hh)[j] = __half_as_ushort(__float2half(hv));
    }
    __syncthreads();
  }
}

// ---------------- attention + emissions (H is f16 now) ----------------

__global__ __launch_bounds__(256) void k_attn(const __half* __restrict__ H,
                                              const float* __restrict__ attnT,
                                              const float* __restrict__ attn_b,
                                              const float* __restrict__ attn_v,
                                              float* __restrict__ scores){
  int tid = threadIdx.x; int base = blockIdx.x*4;
  __shared__ float rows[4*256];
  __shared__ float red[4*256];
  for (int idx = tid; idx < 1024; idx += 256) rows[idx] = __half2float(H[(long)base*256 + idx]);
  __syncthreads();
  float a0=0.f, a1=0.f, a2=0.f, a3=0.f;
  #pragma unroll 4
  for (int k = 0; k < 256; k++){
    float w = attnT[k*256 + tid];
    a0 += w*rows[k]; a1 += w*rows[256+k]; a2 += w*rows[512+k]; a3 += w*rows[768+k];
  }
  float ab = attn_b[tid], av = attn_v[tid];
  red[tid]       = tanhf_(a0 + ab)*av;
  red[256 + tid] = tanhf_(a1 + ab)*av;
  red[512 + tid] = tanhf_(a2 + ab)*av;
  red[768 + tid] = tanhf_(a3 + ab)*av;
  __syncthreads();
  for (int s = 128; s > 0; s >>= 1){
    if (tid < s){
      red[tid] += red[tid+s]; red[256+tid] += red[256+tid+s];
      red[512+tid] += red[512+tid+s]; red[768+tid] += red[768+tid+s];
    }
    __syncthreads();
  }
  if (tid < 4) scores[base + tid] = red[tid*256];
}

__global__ __launch_bounds__(256) void k_softmax(float* __restrict__ scores){
  int b = blockIdx.x, tid = threadIdx.x;
  __shared__ float red[256];
  float s = scores[b*256 + tid];
  red[tid] = s; __syncthreads();
  for (int st = 128; st > 0; st >>= 1){ if (tid < st) red[tid] = fmaxf(red[tid], red[tid+st]); __syncthreads(); }
  float m = red[0]; __syncthreads();
  float e = __expf(s - m);
  red[tid] = e; __syncthreads();
  for (int st = 128; st > 0; st >>= 1){ if (tid < st) red[tid] += red[tid+st]; __syncthreads(); }
  float inv = 1.0f / red[0];
  scores[b*256 + tid] = e * inv;
}

__global__ __launch_bounds__(256) void k_emis(const __half* __restrict__ H, const float* __restrict__ scores,
                                              const float* __restrict__ emis_w, const float* __restrict__ emis_b,
                                              float* __restrict__ emis){
  int tid = threadIdx.x; int base = blockIdx.x*4;
  int r = tid >> 6, j = tid & 63;
  __shared__ float rows[4*256];
  for (int idx = tid; idx < 1024; idx += 256) rows[idx] = __half2float(H[(long)base*256 + idx]);
  __syncthreads();
  if (j < 9){
    float acc = 0.f;
    #pragma unroll 4
    for (int k = 0; k < 256; k++) acc += rows[r*256 + k] * emis_w[j*256 + k];
    int tok = base + r;
    emis[tok*9 + j] = scores[tok]*acc + emis_b[j];
  }
}

// ---------------- CRF ----------------

__global__ __launch_bounds__(64) void k_crf(const float* __restrict__ emis, const float* __restrict__ trans,
                                            const float* __restrict__ startv, const float* __restrict__ endv,
                                            float* __restrict__ logZ){
  int b = blockIdx.x; int j = threadIdx.x;
  bool act = (j < 9);
  float alpha = act ? (startv[j] + emis[(b*256)*9 + j]) : -1e30f;
  float trow[9];
  #pragma unroll
  for (int i = 0; i < 9; i++) trow[i] = act ? trans[i*9 + j] : 0.f;
  for (int t = 1; t < 256; t++){
    float v[9];
    #pragma unroll
    for (int i = 0; i < 9; i++) v[i] = __shfl(alpha, i) + trow[i];
    float m = v[0];
    #pragma unroll
    for (int i = 1; i < 9; i++) m = fmaxf(m, v[i]);
    float ssum = 0.f;
    #pragma unroll
    for (int i = 0; i < 9; i++) ssum += expf(v[i] - m);
    float e = act ? emis[(b*256 + t)*9 + j] : 0.f;
    alpha = m + logf(ssum) + e;
  }
  float v = act ? (alpha + endv[j]) : -1e30f;
  float vv[9];
  float m = -1e30f;
  #pragma unroll
  for (int i = 0; i < 9; i++){ vv[i] = __shfl(v, i); m = fmaxf(m, vv[i]); }
  float ssum = 0.f;
  #pragma unroll
  for (int i = 0; i < 9; i++) ssum += expf(vv[i] - m);
  if (j == 0) logZ[b] = m + logf(ssum);
}

__global__ __launch_bounds__(256) void k_num(const int* __restrict__ tags, const float* __restrict__ emis,
                                             const float* __restrict__ trans, const float* __restrict__ startv,
                                             const float* __restrict__ endv, float* __restrict__ num){
  int b = blockIdx.x, t = threadIdx.x;
  int tg = tags[b*256 + t];
  float v = emis[(b*256 + t)*9 + tg];
  if (t > 0) v += trans[tags[b*256 + t - 1]*9 + tg];
  __shared__ float red[256];
  red[t] = v; __syncthreads();
  for (int s = 128; s > 0; s >>= 1){ if (t < s) red[t] += red[t+s]; __syncthreads(); }
  if (t == 0) num[b] = red[0] + startv[tags[b*256]] + endv[tags[b*256 + 255]];
}

__global__ __launch_bounds__(64) void k_final(const float* __restrict__ logZ, const float* __restrict__ num,
                                              float* __restrict__ out){
  int b = threadIdx.x;
  float v = logZ[b] - num[b];
  for (int s = 32; s > 0; s >>= 1) v += __shfl_down(v, s);
  if (b == 0) out[0] = v * (1.0f/64.0f);
}

__global__ void k_diag(float* __restrict__ out, float ws_mb){
  if (threadIdx.x == 0) out[0] = -ws_mb;
}

// ---------------- launcher ----------------

extern "C" void kernel_launch(void* const* d_in, const int* in_sizes, int n_in,
                              void* d_out, int out_size, void* d_ws, size_t ws_size,
                              hipStream_t stream) {
  const int*   word_ids   = (const int*)  d_in[0];
  const int*   char_ids   = (const int*)  d_in[1];
  const int*   tags       = (const int*)  d_in[3];
  const float* word_emb   = (const float*)d_in[4];
  const float* emb_cnn    = (const float*)d_in[5];
  const float* conv_w3    = (const float*)d_in[6];
  const float* conv_b3    = (const float*)d_in[7];
  const float* conv_w5    = (const float*)d_in[8];
  const float* conv_b5    = (const float*)d_in[9];
  const float* conv_w7    = (const float*)d_in[10];
  const float* conv_b7    = (const float*)d_in[11];
  const float* emb_lstm   = (const float*)d_in[12];
  const float* cl_wih_f   = (const float*)d_in[13];
  const float* cl_whh_f   = (const float*)d_in[14];
  const float* cl_bih_f   = (const float*)d_in[15];
  const float* cl_bhh_f   = (const float*)d_in[16];
  const float* cl_wih_b   = (const float*)d_in[17];
  const float* cl_whh_b   = (const float*)d_in[18];
  const float* cl_bih_b   = (const float*)d_in[19];
  const float* cl_bhh_b   = (const float*)d_in[20];
  const float* fuse_w     = (const float*)d_in[21];
  const float* fuse_b     = (const float*)d_in[22];
  const float* ctx_wih_f  = (const float*)d_in[23];
  const float* ctx_whh_f  = (const float*)d_in[24];
  const float* ctx_bih_f  = (const float*)d_in[25];
  const float* ctx_bhh_f  = (const float*)d_in[26];
  const float* ctx_wih_b  = (const float*)d_in[27];
  const float* ctx_whh_b  = (const float*)d_in[28];
  const float* ctx_bih_b  = (const float*)d_in[29];
  const float* ctx_bhh_b  = (const float*)d_in[30];
  const float* attn_w     = (const float*)d_in[31];
  const float* attn_b     = (const float*)d_in[32];
  const float* attn_v     = (const float*)d_in[33];
  const float* emis_w     = (const float*)d_in[34];
  const float* emis_b     = (const float*)d_in[35];
  const float* crf_start  = (const float*)d_in[36];
  const float* crf_end    = (const float*)d_in[37];
  const float* crf_trans  = (const float*)d_in[38];
  float* out = (float*)d_out;
  float* ws  = (float*)d_ws;

  // workspace layout (float slots):
  const size_t OFF_A      = 0;          // 8388608
  const size_t OFF_FUSED  = 8388608;    // 3276800 (H f16 aliases this later)
  const size_t OFF_SCORES = 11665408;   // 16384
  const size_t OFF_EMIS   = 11681792;   // 147456
  const size_t OFF_WIHP   = 11829248;   // 102400
  const size_t OFF_WHHQ   = 11931648;   // 65536
  const size_t OFF_BIASC  = 11997184;   // 1024
  const size_t OFF_P4I    = 11998208;   // 41600 (2*100*208 f32)
  const size_t OFF_Q      = 12039808;   // 48000
  const size_t OFF_WB     = 12087808;   // 13312 (26624 ushort)
  const size_t OFF_WFT    = 12101120;   // 79200
  const size_t OFF_ATTNT  = 12180320;   // 65536
  const size_t OFF_NUM    = 12245856;   // 64
  const size_t OFF_LOGZ   = 12245920;   // 64
  const size_t TOTAL_FLOATS = 12245984; // 48,983,936 bytes (~48.98 MB)

  if (ws_size < TOTAL_FLOATS * sizeof(float)) {
    k_diag<<<1, 64, 0, stream>>>(out, (float)((double)ws_size / (1024.0*1024.0)));
    return;
  }

  float* combined = ws + OFF_A;
  __half* Gx      = (__half*)(ws + OFF_A);
  float* fused    = ws + OFF_FUSED;
  __half* H       = (__half*)(ws + OFF_FUSED);
  float* scores   = ws + OFF_SCORES;
  float* emis     = ws + OFF_EMIS;
  unsigned int* wihP = (unsigned int*)(ws + OFF_WIHP);
  unsigned int* whhQ = (unsigned int*)(ws + OFF_WHHQ);
  float* biasc    = ws + OFF_BIASC;
  float* P4I      = ws + OFF_P4I;
  float* Q        = ws + OFF_Q;
  unsigned short* WBu = (unsigned short*)(ws + OFF_WB);
  float* wFT      = ws + OFF_WFT;
  float* attnT    = ws + OFF_ATTNT;
  float* num      = ws + OFF_NUM;
  float* logZ     = ws + OFF_LOGZ;

  // prep
  k_transpose<<<(200*396 + 255)/256, 256, 0, stream>>>(fuse_w, wFT, 200, 396);
  k_transpose<<<(256*256 + 255)/256, 256, 0, stream>>>(attn_w, attnT, 256, 256);
  k_prep_ctx<<<(2*100*512 + 2*16*512*4 + 1024 + 255)/256, 256, 0, stream>>>(
      ctx_wih_f, ctx_whh_f, ctx_bih_f, ctx_bhh_f,
      ctx_wih_b, ctx_whh_b, ctx_bih_b, ctx_bhh_b, wihP, whhQ, biasc);
  k_prep_p4i<<<(41600 + 255)/256, 256, 0, stream>>>(
      emb_lstm, cl_wih_f, cl_bih_f, cl_bhh_f, cl_wih_b, cl_bih_b, cl_bhh_b, P4I);
  k_prep_wb<<<(26624 + 255)/256, 256, 0, stream>>>(cl_whh_f, cl_whh_b, WBu);
  k_prep_Q<<<(48000 + 255)/256, 256, 0, stream>>>(emb_cnn, conv_w3, conv_w5, conv_w7, Q);

  // features
  k_gather<<<(NB_B*NT*200 + 255)/256, 256, 0, stream>>>(word_ids, word_emb, combined);
  k_cnn2<3><<<NB_B*NT/16, 512, 0, stream>>>(char_ids, Q,         conv_b3, combined, 0);
  k_cnn2<5><<<NB_B*NT/16, 512, 0, stream>>>(char_ids, Q + 9600,  conv_b5, combined, 32);
  k_cnn2<7><<<NB_B*NT/16, 512, 0, stream>>>(char_ids, Q + 25600, conv_b7, combined, 64);
  k_char_lstm<<<dim3(NB_B*NT/64, 2), 256, 0, stream>>>(char_ids, P4I, WBu, combined);
  k_fuse<<<NB_B*NT/4, 256, 0, stream>>>(combined, wFT, fuse_b, fused);

  // context LSTM: parallel x-projection (Gx overwrites dead combined),
  // then recurrence-only kernel (H f16 overwrites dead fused)
  k_gx<<<dim3(NB_B*NT/8, 2), 512, 0, stream>>>(fused, wihP, biasc, Gx);
  k_ctx_rec<<<dim3(NB_B, 2), 512, 0, stream>>>(Gx, (const uint4*)whhQ, H);

  // attention + emissions
  k_attn<<<NB_B*NT/4, 256, 0, stream>>>(H, attnT, attn_b, attn_v, scores);
  k_softmax<<<NB_B, 256, 0, stream>>>(scores);
  k_emis<<<NB_B*NT/4, 256, 0, stream>>>(H, scores, emis_w, emis_b, emis);

  // CRF
  k_crf<<<NB_B, 64, 0, stream>>>(emis, crf_trans, crf_start, crf_end, logZ);
  k_num<<<NB_B, 256, 0, stream>>>(tags, emis, crf_trans, crf_start, crf_end, num);
  k_final<<<1, 64, 0, stream>>>(logZ, num, out);
}